// Round 1
// baseline (17733.586 us; speedup 1.0000x reference)
//
#include <hip/hip_runtime.h>
#include <math.h>

// Grid-LSTM B=128, T=256, L=2, H=512.
// Persistent cooperative kernel: 513 rounds (A: {c00(t), c11(t-1)}, B: {c01(t), c10(t)}),
// weights LDS-resident for the whole sequence, device-wide barrier between rounds.

static constexpr int Hn = 512;
static constexpr int Bn = 128;
static constexpr int Tn = 256;
static constexpr long THn = (long)Tn * Hn;   // 131072
static constexpr long LBH = (long)Bn * Hn;   // 65536
static constexpr int NBLK = 256;
static constexpr int NROUND = 2 * Tn + 1;    // 513

typedef __attribute__((ext_vector_type(8))) short short8;
typedef __attribute__((ext_vector_type(4))) float floatx4;

__device__ __forceinline__ unsigned short f2bf(float f) {
    unsigned u = __builtin_bit_cast(unsigned, f);
    unsigned r = u + 0x7FFFu + ((u >> 16) & 1u);   // RNE
    return (unsigned short)(r >> 16);
}
__device__ __forceinline__ unsigned pk2(float a, float b) {
    return (unsigned)f2bf(a) | ((unsigned)f2bf(b) << 16);
}
__device__ __forceinline__ float sel4(float a, float b, float cc, float d, int s) {
    float r = a;
    r = (s == 1) ? b : r;
    r = (s == 2) ? cc : r;
    r = (s == 3) ? d : r;
    return r;
}
__device__ __forceinline__ float selc(floatx4 v, int s) {
    float r = v[0];
    r = (s == 1) ? v[1] : r;
    r = (s == 2) ? v[2] : r;
    r = (s == 3) ? v[3] : r;
    return r;
}

struct Params {
    const float* H0in;
    const float* Wih; const float* Whh;
    const float* bih; const float* bhh;
    unsigned short* h0A; unsigned short* h0B;
    unsigned short* H1b;        // [2 parity][2 layer][B][H] bf16
    float* m0; float* M1;       // M1: [2 layer][B][H] fp32
    float* outH0; float* outH1; float* outM0; float* outM1;
    unsigned* barCnt; unsigned* barGen;
};

struct RoundDesc {
    const unsigned short* x;    // k<512 operand (stride 512, bf16)
    const unsigned short* hB;   // k>=512 operand bf16 (stride hs) — or
    const float* hF;            //   fp32 (c00's H0in slice)
    long hs;
    const float* cin;           // fp32 stride 512, or null (zeros)
    unsigned short* hOutB;      // bf16 recurrent h out, stride 512
    float* cOut; long cs;       // fp32 c out
    float* hOut2; long h2s;     // optional fp32 h out
    float* cOut2; long c2s;     // optional fp32 c out
};

// Sense-reversing device-wide barrier (gen = completed rounds).
__device__ __forceinline__ void gridBarrier(unsigned* cnt, unsigned* gen, unsigned target) {
    __syncthreads();
    if (threadIdx.x == 0) {
        __threadfence();  // make this block's stores device-visible
        unsigned prev = __hip_atomic_fetch_add(cnt, 1u, __ATOMIC_ACQ_REL, __HIP_MEMORY_SCOPE_AGENT);
        if (prev == (unsigned)(NBLK - 1)) {
            __hip_atomic_store(cnt, 0u, __ATOMIC_RELAXED, __HIP_MEMORY_SCOPE_AGENT);
            __hip_atomic_fetch_add(gen, 1u, __ATOMIC_RELEASE, __HIP_MEMORY_SCOPE_AGENT);
        } else {
            while (__hip_atomic_load(gen, __ATOMIC_ACQUIRE, __HIP_MEMORY_SCOPE_AGENT) < target) {
                __builtin_amdgcn_s_sleep(2);
            }
        }
    }
    __syncthreads();
}

// Load one weight chunk (cell, jt): 32 W-rows (row = jj*4 + g, jj=0..7, g=0..3) x K=1024,
// fp32 -> bf16, XOR-swizzled ((row&7)<<4 on byte col) into LDS. 256 threads cooperate.
__device__ __forceinline__ void loadChunk(char* dst, const float* Wih, const float* Whh,
                                          int cell, int jt, int tid) {
    const int rw = tid >> 3;              // 0..31
    const int jj = rw >> 2, g = rw & 3;
    const long nrow = (long)cell * 2048 + (long)g * 512 + jt * 8 + jj;
    const float* baseI = Wih + nrow * 512;
    const float* baseH = Whh + nrow * 512;
    const int k0 = (tid & 7) * 128;
    #pragma unroll
    for (int i = 0; i < 16; ++i) {
        int k = k0 + i * 8;
        const float* src = (k < 512) ? (baseI + k) : (baseH + (k - 512));
        float4 v0 = *(const float4*)src;
        float4 v1 = *(const float4*)(src + 4);
        uint4 w = {pk2(v0.x, v0.y), pk2(v0.z, v0.w), pk2(v1.x, v1.y), pk2(v1.z, v1.w)};
        int byteCol = (k * 2) ^ ((rw & 7) << 4);
        *(uint4*)(dst + (long)rw * 2048 + byteCol) = w;
    }
}

// One cell GEMM round for this block's 64 rows: K=1024, 16 output cols (8 j x ... as 2 nf of
// 16 MFMA-cols = (jj,g)); per wave 16 rows, 2 accs, 64 MFMA. Fused LSTM epilogue.
template<bool HFP32>
__device__ __forceinline__ void runCell(const RoundDesc& D, const char* chunk,
                                        const float bias[2][4], int jt, int row0,
                                        int c, int q) {
    floatx4 acc0 = {0.f, 0.f, 0.f, 0.f};
    floatx4 acc1 = {0.f, 0.f, 0.f, 0.f};
    const long arow = row0 + c;

    // ---- prefetch all 32 A-frags (16B each) into registers ----
    short8 afr[32];
    #pragma unroll
    for (int ks = 0; ks < 16; ++ks)
        afr[ks] = *(const short8*)(D.x + arow * 512 + ks * 32 + q * 8);
    #pragma unroll
    for (int ks = 0; ks < 16; ++ks) {
        if constexpr (HFP32) {
            const float* hp = D.hF + arow * D.hs + ks * 32 + q * 8;
            float4 v0 = *(const float4*)hp;
            float4 v1 = *(const float4*)(hp + 4);
            uint4 w = {pk2(v0.x, v0.y), pk2(v0.z, v0.w), pk2(v1.x, v1.y), pk2(v1.z, v1.w)};
            afr[16 + ks] = __builtin_bit_cast(short8, w);
        } else {
            afr[16 + ks] = *(const short8*)(D.hB + arow * D.hs + ks * 32 + q * 8);
        }
    }

    // ---- K loop: B-frags from LDS chunk (swizzled), 2 MFMA per ks ----
    const int key = (c & 7) << 4;
    const char* rowp0 = chunk + (long)c * 2048;
    #pragma unroll
    for (int ks = 0; ks < 32; ++ks) {
        int off = ((ks * 64 + q * 16) ^ key);
        short8 b0 = *(const short8*)(rowp0 + off);
        short8 b1 = *(const short8*)(rowp0 + 32768 + off);
        acc0 = __builtin_amdgcn_mfma_f32_16x16x32_bf16(afr[ks], b0, acc0, 0, 0, 0);
        acc1 = __builtin_amdgcn_mfma_f32_16x16x32_bf16(afr[ks], b1, acc1, 0, 0, 0);
    }

    // ---- fused epilogue: gather 4 gates within each lane-quad, lane stores row q*4+g ----
    const int g = c & 3;
    #pragma unroll
    for (int nf = 0; nf < 2; ++nf) {
        floatx4 acc = nf ? acc1 : acc0;
        float s0 = selc(acc, g);
        float s1 = __shfl_xor(selc(acc, g ^ 1), 1);
        float s2 = __shfl_xor(selc(acc, g ^ 2), 2);
        float s3 = __shfl_xor(selc(acc, g ^ 3), 3);
        float iv = sel4(s0, s1, s2, s3, g)     + bias[nf][0];
        float fv = sel4(s0, s1, s2, s3, g ^ 1) + bias[nf][1];
        float gv = sel4(s0, s1, s2, s3, g ^ 2) + bias[nf][2];
        float ov = sel4(s0, s1, s2, s3, g ^ 3) + bias[nf][3];

        const int row = row0 + q * 4 + g;
        const int jglob = jt * 8 + nf * 4 + (c >> 2);
        float cold = D.cin ? D.cin[(long)row * 512 + jglob] : 0.f;
        float si = 1.f / (1.f + expf(-iv));
        float sf = 1.f / (1.f + expf(-fv));
        float so = 1.f / (1.f + expf(-ov));
        float cn = sf * cold + si * tanhf(gv);
        float hn = so * tanhf(cn);
        D.hOutB[(long)row * 512 + jglob] = f2bf(hn);
        D.cOut[(long)row * D.cs + jglob] = cn;
        if (D.hOut2) D.hOut2[(long)row * D.h2s + jglob] = hn;
        if (D.cOut2) D.cOut2[(long)row * D.c2s + jglob] = cn;
    }
}

__global__ __launch_bounds__(256, 1) void grid_lstm_persist(Params P) {
    __shared__ char smem[2 * 65536];   // [A-role chunk][B-role chunk]

    const int tid = threadIdx.x;
    const int lane = tid & 63;
    const int wid = tid >> 6;
    const int c = lane & 15;
    const int q = lane >> 4;
    const int blk = blockIdx.x;
    const int pair = blk >> 1;
    const int half = blk & 1;          // row half: rows [half*64, half*64+64)
    const int jt = pair & 63;
    const bool hiPair = pair >= 64;
    const int cellA = hiPair ? 3 : 0;  // c11 : c00
    const int cellB = hiPair ? 2 : 1;  // c10 : c01

    // ---- prologue: weights fp32 -> bf16 -> LDS (once), biases -> registers ----
    loadChunk(smem,         P.Wih, P.Whh, cellA, jt, tid);
    loadChunk(smem + 65536, P.Wih, P.Whh, cellB, jt, tid);

    float biasA[2][4], biasB[2][4];
    {
        const int cu = c >> 2;
        #pragma unroll
        for (int nf = 0; nf < 2; ++nf) {
            int j = jt * 8 + nf * 4 + cu;
            #pragma unroll
            for (int g = 0; g < 4; ++g) {
                long ia = (long)cellA * 2048 + (long)g * 512 + j;
                long ib = (long)cellB * 2048 + (long)g * 512 + j;
                biasA[nf][g] = P.bih[ia] + P.bhh[ia];
                biasB[nf][g] = P.bih[ib] + P.bhh[ib];
            }
        }
    }
    __syncthreads();

    const int row0 = half * 64 + wid * 16;

    for (int r = 0; r < NROUND; ++r) {
        const int t = r >> 1;
        const bool stB = (r & 1) != 0;
        RoundDesc D{};
        bool active = true;
        bool hfp32 = false;

        if (!stB) {
            if (!hiPair) {                      // c00(t): x=H1[p][0], h=H0in[t] fp32
                active = (t < Tn);
                if (active) {
                    int p = t & 1;
                    D.x = P.H1b + ((long)p * 2 + 0) * LBH;
                    D.hF = P.H0in + (long)t * Hn; D.hs = THn; hfp32 = true;
                    D.cin = nullptr;
                    D.hOutB = P.h0A; D.cOut = P.m0; D.cs = 512;
                }
            } else {                            // c11(t-1)
                int tc = t - 1;
                active = (tc >= 0);
                if (active) {
                    int p = tc & 1;
                    D.x = P.h0B;
                    D.hB = P.H1b + ((long)p * 2 + 1) * LBH; D.hs = 512;
                    D.cin = P.M1 + LBH;
                    D.hOutB = P.H1b + ((long)(1 - p) * 2 + 1) * LBH;
                    D.cOut = P.M1 + LBH; D.cs = 512;
                    if (tc == Tn - 1) {
                        D.hOut2 = P.outH1 + Hn; D.h2s = 1024;
                        D.cOut2 = P.outM1 + Hn; D.c2s = 1024;
                    }
                }
            }
        } else {
            int p = t & 1;
            if (!hiPair) {                      // c01(t): x=h0A, h=H1[p][0]
                D.x = P.h0A;
                D.hB = P.H1b + ((long)p * 2 + 0) * LBH; D.hs = 512;
                D.cin = P.M1;
                D.hOutB = P.H1b + ((long)(1 - p) * 2 + 0) * LBH;
                D.cOut = P.M1; D.cs = 512;
                if (t == Tn - 1) {
                    D.hOut2 = P.outH1; D.h2s = 1024;
                    D.cOut2 = P.outM1; D.c2s = 1024;
                }
            } else {                            // c10(t): x=H1[p][1], h=h0A
                D.x = P.H1b + ((long)p * 2 + 1) * LBH;
                D.hB = P.h0A; D.hs = 512;
                D.cin = P.m0;
                D.hOutB = P.h0B;
                D.cOut = P.outM0 + (long)t * Hn; D.cs = THn;
                D.hOut2 = P.outH0 + (long)t * Hn; D.h2s = THn;
            }
        }

        if (active) {
            const char* chunk = stB ? (smem + 65536) : smem;
            const float (*bias)[4] = stB ? biasB : biasA;
            if (hfp32) runCell<true>(D, chunk, bias, jt, row0, c, q);
            else       runCell<false>(D, chunk, bias, jt, row0, c, q);
        }
        if (r + 1 < NROUND) gridBarrier(P.barCnt, P.barGen, (unsigned)(r + 1));
    }
}

extern "C" void kernel_launch(void* const* d_in, const int* in_sizes, int n_in,
                              void* d_out, int out_size, void* d_ws, size_t ws_size,
                              hipStream_t stream) {
    (void)in_sizes; (void)n_in; (void)out_size; (void)ws_size;
    const float* H0in = (const float*)d_in[0];
    const float* Wih  = (const float*)d_in[1];
    const float* Whh  = (const float*)d_in[2];
    const float* bih  = (const float*)d_in[3];
    const float* bhh  = (const float*)d_in[4];
    float* out = (float*)d_out;

    // workspace: bf16 recurrent bufs + fp32 cell states + barrier counters (~1.6 MB)
    unsigned short* h0A = (unsigned short*)d_ws;
    unsigned short* h0B = h0A + LBH;
    unsigned short* H1b = h0B + LBH;                  // [2][2][B][H] bf16
    float* m0 = (float*)(H1b + 4 * LBH);
    float* M1 = m0 + LBH;                             // [2][B][H] fp32
    unsigned* bar = (unsigned*)(M1 + 2 * LBH);

    size_t zeroBytes = (size_t)((char*)(bar + 64) - (char*)d_ws);
    hipMemsetAsync(d_ws, 0, zeroBytes, stream);

    Params P;
    P.H0in = H0in; P.Wih = Wih; P.Whh = Whh; P.bih = bih; P.bhh = bhh;
    P.h0A = h0A; P.h0B = h0B; P.H1b = H1b; P.m0 = m0; P.M1 = M1;
    P.outH0 = out;
    P.outH1 = out + (long)Bn * THn;
    P.outM0 = P.outH1 + 2 * LBH;
    P.outM1 = P.outM0 + (long)Bn * THn;
    P.barCnt = bar; P.barGen = bar + 32;

    void* args[] = {&P};
    hipLaunchCooperativeKernel((void*)grid_lstm_persist, dim3(NBLK), dim3(256),
                               args, 0, stream);
}

// Round 2
// 9903.746 us; speedup vs baseline: 1.7906x; 1.7906x over previous
//
#include <hip/hip_runtime.h>
#include <math.h>

// Grid-LSTM B=128, T=256, L=2, H=512.
// Persistent cooperative kernel: 513 rounds (A: {c00(t), c11(t-1)}, B: {c01(t), c10(t)}),
// weights LDS-resident for the whole sequence, device-wide barrier between rounds.
// v2: relaxed-poll two-level barrier (no per-poll L2 invalidate); LDS chunk stored in
// MFMA-fragment order [ks][row][q] so B-frag ds_reads are contiguous (conflict-free).

static constexpr int Hn = 512;
static constexpr int Bn = 128;
static constexpr int Tn = 256;
static constexpr long THn = (long)Tn * Hn;   // 131072
static constexpr long LBH = (long)Bn * Hn;   // 65536
static constexpr int NBLK = 256;
static constexpr int NROUND = 2 * Tn + 1;    // 513

typedef __attribute__((ext_vector_type(8))) short short8;
typedef __attribute__((ext_vector_type(4))) float floatx4;

__device__ __forceinline__ unsigned short f2bf(float f) {
    unsigned u = __builtin_bit_cast(unsigned, f);
    unsigned r = u + 0x7FFFu + ((u >> 16) & 1u);   // RNE
    return (unsigned short)(r >> 16);
}
__device__ __forceinline__ unsigned pk2(float a, float b) {
    return (unsigned)f2bf(a) | ((unsigned)f2bf(b) << 16);
}
__device__ __forceinline__ float sel4(float a, float b, float cc, float d, int s) {
    float r = a;
    r = (s == 1) ? b : r;
    r = (s == 2) ? cc : r;
    r = (s == 3) ? d : r;
    return r;
}
__device__ __forceinline__ float selc(floatx4 v, int s) {
    float r = v[0];
    r = (s == 1) ? v[1] : r;
    r = (s == 2) ? v[2] : r;
    r = (s == 3) ? v[3] : r;
    return r;
}

struct Params {
    const float* H0in;
    const float* Wih; const float* Whh;
    const float* bih; const float* bhh;
    unsigned short* h0A; unsigned short* h0B;
    unsigned short* H1b;        // [2 parity][2 layer][B][H] bf16
    float* m0; float* M1;       // M1: [2 layer][B][H] fp32
    float* outH0; float* outH1; float* outM0; float* outM1;
    unsigned* bar;              // leaf[i] at bar[i*16], i=0..7; root at bar[128]
};

struct RoundDesc {
    const unsigned short* x;    // k<512 operand (stride 512, bf16)
    const unsigned short* hB;   // k>=512 operand bf16 (stride hs) — or
    const float* hF;            //   fp32 (c00's H0in slice)
    long hs;
    const float* cin;           // fp32 stride 512, or null (zeros)
    unsigned short* hOutB;      // bf16 recurrent h out, stride 512
    float* cOut; long cs;       // fp32 c out
    float* hOut2; long h2s;     // optional fp32 h out
    float* cOut2; long c2s;     // optional fp32 c out
};

// Two-level device-wide barrier. Monotone counters (no reset / ABA):
// each round adds 32 per leaf, 8 to root. Waiters poll root RELAXED (no cache
// ops per poll — the per-poll acquire/buffer_inv was the v1 killer), then do ONE
// acquire load to pull in the round's cross-XCD writes.
__device__ __forceinline__ void gridBarrier(unsigned* bar, int leafIdx, unsigned r) {
    __syncthreads();
    if (threadIdx.x == 0) {
        __threadfence();  // belt-and-suspenders: drain this block's stores to L3
        unsigned prev = __hip_atomic_fetch_add(&bar[leafIdx * 16], 1u,
                                               __ATOMIC_ACQ_REL, __HIP_MEMORY_SCOPE_AGENT);
        if ((prev & 31u) == 31u) {
            __hip_atomic_fetch_add(&bar[128], 1u, __ATOMIC_ACQ_REL, __HIP_MEMORY_SCOPE_AGENT);
        }
        const unsigned target = 8u * (r + 1u);
        while (__hip_atomic_load(&bar[128], __ATOMIC_RELAXED, __HIP_MEMORY_SCOPE_AGENT) < target) {
            __builtin_amdgcn_s_sleep(2);
        }
        // single acquire (one buffer_inv) to make other XCDs' writes visible
        (void)__hip_atomic_load(&bar[128], __ATOMIC_ACQUIRE, __HIP_MEMORY_SCOPE_AGENT);
    }
    __syncthreads();
}

// Load one weight chunk (cell, jt) into LDS in MFMA-fragment granule order:
// granule (ks, row, q) at byte ks*2048 + row*64 + q*16 holds B[row][k], k=ks*32+q*8..+8.
// row = jj*4+g (jj=0..7, g=0..3), K=1024 spanning [Wih | Whh]. 256 threads cooperate.
__device__ __forceinline__ void loadChunk(char* dst, const float* Wih, const float* Whh,
                                          int cell, int jt, int tid) {
    const int rw = tid >> 3;              // 0..31
    const int jj = rw >> 2, g = rw & 3;
    const long nrow = (long)cell * 2048 + (long)g * 512 + jt * 8 + jj;
    const float* baseI = Wih + nrow * 512;
    const float* baseH = Whh + nrow * 512;
    const int k0 = (tid & 7) * 128;
    #pragma unroll
    for (int i = 0; i < 16; ++i) {
        int k = k0 + i * 8;
        const float* src = (k < 512) ? (baseI + k) : (baseH + (k - 512));
        float4 v0 = *(const float4*)src;
        float4 v1 = *(const float4*)(src + 4);
        uint4 w = {pk2(v0.x, v0.y), pk2(v0.z, v0.w), pk2(v1.x, v1.y), pk2(v1.z, v1.w)};
        int byteOff = (k >> 5) * 2048 + rw * 64 + ((k >> 3) & 3) * 16;
        *(uint4*)(dst + byteOff) = w;
    }
}

// One cell GEMM round for this block's 64 rows: K=1024, 32 gate-cols.
// Per wave: 16 rows, 2 accs (chunk rows c and c+16), 64 MFMA. Fused LSTM epilogue.
template<bool HFP32>
__device__ __forceinline__ void runCell(const RoundDesc& D, const char* chunk,
                                        const float bias[2][4], int jt, int row0,
                                        int c, int q) {
    floatx4 acc0 = {0.f, 0.f, 0.f, 0.f};
    floatx4 acc1 = {0.f, 0.f, 0.f, 0.f};
    const long arow = row0 + c;

    // ---- prefetch all 32 A-frags (16B each) into registers ----
    short8 afr[32];
    #pragma unroll
    for (int ks = 0; ks < 16; ++ks)
        afr[ks] = *(const short8*)(D.x + arow * 512 + ks * 32 + q * 8);
    #pragma unroll
    for (int ks = 0; ks < 16; ++ks) {
        if constexpr (HFP32) {
            const float* hp = D.hF + arow * D.hs + ks * 32 + q * 8;
            float4 v0 = *(const float4*)hp;
            float4 v1 = *(const float4*)(hp + 4);
            uint4 w = {pk2(v0.x, v0.y), pk2(v0.z, v0.w), pk2(v1.x, v1.y), pk2(v1.z, v1.w)};
            afr[16 + ks] = __builtin_bit_cast(short8, w);
        } else {
            afr[16 + ks] = *(const short8*)(D.hB + arow * D.hs + ks * 32 + q * 8);
        }
    }

    // ---- K loop: B-frags from LDS. Wave's 64 lanes (c*4+q) read one contiguous
    // 1024 B block per fragment -> conflict-free; offsets are compile-time imms.
    const char* base = chunk + (long)(c * 64 + q * 16);
    #pragma unroll
    for (int ks = 0; ks < 32; ++ks) {
        short8 b0 = *(const short8*)(base + ks * 2048);
        short8 b1 = *(const short8*)(base + ks * 2048 + 1024);
        acc0 = __builtin_amdgcn_mfma_f32_16x16x32_bf16(afr[ks], b0, acc0, 0, 0, 0);
        acc1 = __builtin_amdgcn_mfma_f32_16x16x32_bf16(afr[ks], b1, acc1, 0, 0, 0);
    }

    // ---- fused epilogue: gather 4 gates within each lane-quad, lane stores row q*4+g ----
    const int g = c & 3;
    #pragma unroll
    for (int nf = 0; nf < 2; ++nf) {
        floatx4 acc = nf ? acc1 : acc0;
        float s0 = selc(acc, g);
        float s1 = __shfl_xor(selc(acc, g ^ 1), 1);
        float s2 = __shfl_xor(selc(acc, g ^ 2), 2);
        float s3 = __shfl_xor(selc(acc, g ^ 3), 3);
        float iv = sel4(s0, s1, s2, s3, g)     + bias[nf][0];
        float fv = sel4(s0, s1, s2, s3, g ^ 1) + bias[nf][1];
        float gv = sel4(s0, s1, s2, s3, g ^ 2) + bias[nf][2];
        float ov = sel4(s0, s1, s2, s3, g ^ 3) + bias[nf][3];

        const int row = row0 + q * 4 + g;
        const int jglob = jt * 8 + nf * 4 + (c >> 2);
        float cold = D.cin ? D.cin[(long)row * 512 + jglob] : 0.f;
        float si = 1.f / (1.f + expf(-iv));
        float sf = 1.f / (1.f + expf(-fv));
        float so = 1.f / (1.f + expf(-ov));
        float cn = sf * cold + si * tanhf(gv);
        float hn = so * tanhf(cn);
        D.hOutB[(long)row * 512 + jglob] = f2bf(hn);
        D.cOut[(long)row * D.cs + jglob] = cn;
        if (D.hOut2) D.hOut2[(long)row * D.h2s + jglob] = hn;
        if (D.cOut2) D.cOut2[(long)row * D.c2s + jglob] = cn;
    }
}

__global__ __launch_bounds__(256, 1) void grid_lstm_persist(Params P) {
    __shared__ char smem[2 * 65536];   // [A-role chunk][B-role chunk]

    const int tid = threadIdx.x;
    const int lane = tid & 63;
    const int wid = tid >> 6;
    const int c = lane & 15;
    const int q = lane >> 4;
    const int blk = blockIdx.x;
    const int pair = blk >> 1;
    const int half = blk & 1;          // row half: rows [half*64, half*64+64)
    const int jt = pair & 63;
    const bool hiPair = pair >= 64;
    const int cellA = hiPair ? 3 : 0;  // c11 : c00
    const int cellB = hiPair ? 2 : 1;  // c10 : c01
    const int leafIdx = blk & 7;

    // ---- prologue: weights fp32 -> bf16 -> LDS (once), biases -> registers ----
    loadChunk(smem,         P.Wih, P.Whh, cellA, jt, tid);
    loadChunk(smem + 65536, P.Wih, P.Whh, cellB, jt, tid);

    float biasA[2][4], biasB[2][4];
    {
        const int cu = c >> 2;
        #pragma unroll
        for (int nf = 0; nf < 2; ++nf) {
            int j = jt * 8 + nf * 4 + cu;
            #pragma unroll
            for (int g = 0; g < 4; ++g) {
                long ia = (long)cellA * 2048 + (long)g * 512 + j;
                long ib = (long)cellB * 2048 + (long)g * 512 + j;
                biasA[nf][g] = P.bih[ia] + P.bhh[ia];
                biasB[nf][g] = P.bih[ib] + P.bhh[ib];
            }
        }
    }
    __syncthreads();

    const int row0 = half * 64 + wid * 16;

    for (int r = 0; r < NROUND; ++r) {
        const int t = r >> 1;
        const bool stB = (r & 1) != 0;
        RoundDesc D{};
        bool active = true;
        bool hfp32 = false;

        if (!stB) {
            if (!hiPair) {                      // c00(t): x=H1[p][0], h=H0in[t] fp32
                active = (t < Tn);
                if (active) {
                    int p = t & 1;
                    D.x = P.H1b + ((long)p * 2 + 0) * LBH;
                    D.hF = P.H0in + (long)t * Hn; D.hs = THn; hfp32 = true;
                    D.cin = nullptr;
                    D.hOutB = P.h0A; D.cOut = P.m0; D.cs = 512;
                }
            } else {                            // c11(t-1)
                int tc = t - 1;
                active = (tc >= 0);
                if (active) {
                    int p = tc & 1;
                    D.x = P.h0B;
                    D.hB = P.H1b + ((long)p * 2 + 1) * LBH; D.hs = 512;
                    D.cin = P.M1 + LBH;
                    D.hOutB = P.H1b + ((long)(1 - p) * 2 + 1) * LBH;
                    D.cOut = P.M1 + LBH; D.cs = 512;
                    if (tc == Tn - 1) {
                        D.hOut2 = P.outH1 + Hn; D.h2s = 1024;
                        D.cOut2 = P.outM1 + Hn; D.c2s = 1024;
                    }
                }
            }
        } else {
            int p = t & 1;
            if (!hiPair) {                      // c01(t): x=h0A, h=H1[p][0]
                D.x = P.h0A;
                D.hB = P.H1b + ((long)p * 2 + 0) * LBH; D.hs = 512;
                D.cin = P.M1;
                D.hOutB = P.H1b + ((long)(1 - p) * 2 + 0) * LBH;
                D.cOut = P.M1; D.cs = 512;
                if (t == Tn - 1) {
                    D.hOut2 = P.outH1; D.h2s = 1024;
                    D.cOut2 = P.outM1; D.c2s = 1024;
                }
            } else {                            // c10(t): x=H1[p][1], h=h0A
                D.x = P.H1b + ((long)p * 2 + 1) * LBH;
                D.hB = P.h0A; D.hs = 512;
                D.cin = P.m0;
                D.hOutB = P.h0B;
                D.cOut = P.outM0 + (long)t * Hn; D.cs = THn;
                D.hOut2 = P.outH0 + (long)t * Hn; D.h2s = THn;
            }
        }

        if (active) {
            const char* chunk = stB ? (smem + 65536) : smem;
            const float (*bias)[4] = stB ? biasB : biasA;
            if (hfp32) runCell<true>(D, chunk, bias, jt, row0, c, q);
            else       runCell<false>(D, chunk, bias, jt, row0, c, q);
        }
        if (r + 1 < NROUND) gridBarrier(P.bar, leafIdx, (unsigned)r);
    }
}

extern "C" void kernel_launch(void* const* d_in, const int* in_sizes, int n_in,
                              void* d_out, int out_size, void* d_ws, size_t ws_size,
                              hipStream_t stream) {
    (void)in_sizes; (void)n_in; (void)out_size; (void)ws_size;
    const float* H0in = (const float*)d_in[0];
    const float* Wih  = (const float*)d_in[1];
    const float* Whh  = (const float*)d_in[2];
    const float* bih  = (const float*)d_in[3];
    const float* bhh  = (const float*)d_in[4];
    float* out = (float*)d_out;

    // workspace: bf16 recurrent bufs + fp32 cell states + barrier counters (~1.6 MB)
    unsigned short* h0A = (unsigned short*)d_ws;
    unsigned short* h0B = h0A + LBH;
    unsigned short* H1b = h0B + LBH;                  // [2][2][B][H] bf16
    float* m0 = (float*)(H1b + 4 * LBH);
    float* M1 = m0 + LBH;                             // [2][B][H] fp32
    unsigned* bar = (unsigned*)(M1 + 2 * LBH);        // leaf[8]@stride16 + root@128

    size_t zeroBytes = (size_t)((char*)(bar + 256) - (char*)d_ws);
    hipMemsetAsync(d_ws, 0, zeroBytes, stream);

    Params P;
    P.H0in = H0in; P.Wih = Wih; P.Whh = Whh; P.bih = bih; P.bhh = bhh;
    P.h0A = h0A; P.h0B = h0B; P.H1b = H1b; P.m0 = m0; P.M1 = M1;
    P.outH0 = out;
    P.outH1 = out + (long)Bn * THn;
    P.outM0 = P.outH1 + 2 * LBH;
    P.outM1 = P.outM0 + (long)Bn * THn;
    P.bar = bar;

    void* args[] = {&P};
    hipLaunchCooperativeKernel((void*)grid_lstm_persist, dim3(NBLK), dim3(256),
                               args, 0, stream);
}

// Round 4
// 5653.244 us; speedup vs baseline: 3.1369x; 1.7519x over previous
//
#include <hip/hip_runtime.h>
#include <math.h>

// Grid-LSTM B=128, T=256, L=2, H=512.
// Persistent cooperative kernel: 513 rounds (A: {c00(t), c11(t-1)}, B: {c01(t), c10(t)}),
// weights LDS-resident, device-wide barrier between rounds.
// v4: hybrid coherence. Cross-block STORES are sc1 write-through (no dirty L2 state ->
// no wbl2/threadfence ever). READS are plain cached (L1/L2 absorb the 64x operand
// re-reads), made safe by ONE buffer_inv sc1 per CU per round after the barrier.
// All loads are compiler-managed (v3's inline-asm load hazard removed).

static constexpr int Hn = 512;
static constexpr int Bn = 128;
static constexpr int Tn = 256;
static constexpr long THn = (long)Tn * Hn;   // 131072
static constexpr long LBH = (long)Bn * Hn;   // 65536
static constexpr int NBLK = 256;
static constexpr int NROUND = 2 * Tn + 1;    // 513

typedef __attribute__((ext_vector_type(8))) short short8;
typedef __attribute__((ext_vector_type(4))) float floatx4;

__device__ __forceinline__ unsigned short f2bf(float f) {
    unsigned u = __builtin_bit_cast(unsigned, f);
    unsigned r = u + 0x7FFFu + ((u >> 16) & 1u);   // RNE
    return (unsigned short)(r >> 16);
}
__device__ __forceinline__ unsigned pk2(float a, float b) {
    return (unsigned)f2bf(a) | ((unsigned)f2bf(b) << 16);
}
__device__ __forceinline__ float sel4(float a, float b, float cc, float d, int s) {
    float r = a;
    r = (s == 1) ? b : r;
    r = (s == 2) ? cc : r;
    r = (s == 3) ? d : r;
    return r;
}
__device__ __forceinline__ float selc(floatx4 v, int s) {
    float r = v[0];
    r = (s == 1) ? v[1] : r;
    r = (s == 2) ? v[2] : r;
    r = (s == 3) ? v[3] : r;
    return r;
}

// ---- sc1 write-through stores (device-coherent, bypass L2 dirty state) ----
// Inputs are ready values -> no in-flight-register hazard (unlike asm loads).
__device__ __forceinline__ void st16_sc(unsigned short* p, unsigned short v) {
    asm volatile("global_store_short %0, %1, off sc1" :: "v"(p), "v"(v) : "memory");
}
__device__ __forceinline__ void st32_sc(float* p, float v) {
    asm volatile("global_store_dword %0, %1, off sc1" :: "v"(p), "v"(v) : "memory");
}

struct Params {
    const float* H0in;
    const float* Wih; const float* Whh;
    const float* bih; const float* bhh;
    unsigned short* h0A; unsigned short* h0B;
    unsigned short* H1b;        // [2 parity][2 layer][B][H] bf16
    float* m0;                  // [B][H] fp32 (c00 -> c10 cell state, per timestep)
    float* outH0; float* outH1; float* outM0; float* outM1;
    unsigned* bar;              // leaf[i] at bar[i*16], i=0..7; root at bar[128]
};

struct RoundDesc {
    const unsigned short* x;    // k<512 operand, bf16 state (cached read)
    const unsigned short* hB;   // k>=512 operand, bf16 state (cached read)
    const float* hF;            // k>=512 operand fp32 (c00: H0in slice)
    const float* cin;           // KIND2: m0 (cached read)
    unsigned short* hOutB;      // bf16 recurrent h out (sc1)
    float* coutA;               // KIND0: m0 (sc1). KIND2: outM0+t*Hn (sc1, stride THn)
    long cAs;
    float* hOut2; long h2s;     // fp32 h dump (sc1)
    float* cOut2; long c2s;     // fp32 c dump (sc1, KIND1/3 final round)
};

// Two-level device barrier, all-relaxed atomics (monotone counters).
// Release: sc1 stores drained by vmcnt(0) (LLVM's own sc1-visibility rule).
// Acquire: ONE buffer_inv sc1 per CU (wave 0), vmcnt-tracked, barrier-protected.
__device__ __forceinline__ void gridBarrier(unsigned* bar, int leafIdx, unsigned r) {
    asm volatile("s_waitcnt vmcnt(0)" ::: "memory");   // sc1 stores acked at IF$
    __syncthreads();
    if (threadIdx.x == 0) {
        unsigned prev = __hip_atomic_fetch_add(&bar[leafIdx * 16], 1u,
                                               __ATOMIC_RELAXED, __HIP_MEMORY_SCOPE_AGENT);
        if ((prev & 31u) == 31u) {
            __hip_atomic_fetch_add(&bar[128], 1u, __ATOMIC_RELAXED, __HIP_MEMORY_SCOPE_AGENT);
        }
        const unsigned target = 8u * (r + 1u);
        while (__hip_atomic_load(&bar[128], __ATOMIC_RELAXED, __HIP_MEMORY_SCOPE_AGENT) < target) {
            __builtin_amdgcn_s_sleep(2);
        }
    }
    __syncthreads();
    if (threadIdx.x < 64) {     // one wave invalidates this CU's L1 + XCD L2
        asm volatile("buffer_inv sc1" ::: "memory");
        asm volatile("s_waitcnt vmcnt(0)" ::: "memory");
    }
    __syncthreads();
    asm volatile("" ::: "memory");   // no cached-in-reg state across rounds
}

// Load one weight chunk (cell, jt) into LDS in MFMA-fragment granule order:
// granule (ks, row, q) at byte ks*2048 + row*64 + q*16 holds B[row][k], k=ks*32+q*8..+8.
// row = jj*4+g (jj=0..7, g=0..3), K=1024 spanning [Wih | Whh]. Plain cached loads (RO).
__device__ __forceinline__ void loadChunk(char* dst, const float* Wih, const float* Whh,
                                          int cell, int jt, int tid) {
    const int rw = tid >> 3;              // 0..31
    const int jj = rw >> 2, g = rw & 3;
    const long nrow = (long)cell * 2048 + (long)g * 512 + jt * 8 + jj;
    const float* baseI = Wih + nrow * 512;
    const float* baseH = Whh + nrow * 512;
    const int k0 = (tid & 7) * 128;
    #pragma unroll
    for (int i = 0; i < 16; ++i) {
        int k = k0 + i * 8;
        const float* src = (k < 512) ? (baseI + k) : (baseH + (k - 512));
        float4 v0 = *(const float4*)src;
        float4 v1 = *(const float4*)(src + 4);
        uint4 w = {pk2(v0.x, v0.y), pk2(v0.z, v0.w), pk2(v1.x, v1.y), pk2(v1.z, v1.w)};
        int byteOff = (k >> 5) * 2048 + rw * 64 + ((k >> 3) & 3) * 16;
        *(uint4*)(dst + byteOff) = w;
    }
}

// One cell GEMM round for this block's 64 rows: K=1024, 32 gate-cols.
// KIND: 0=c00 (h=fp32 input, cin=0, cout->m0), 1=c01 (reg cstate),
//       2=c10 (cin=m0, couts dumped), 3=c11 (reg cstate).
template<int KIND>
__device__ __forceinline__ void runCell(const RoundDesc& D, const char* chunk,
                                        const float bias[2][4], int jt, int row0,
                                        int c, int q, float cst[2]) {
    const long arow = row0 + c;
    const int g = c & 3;
    const int cu = c >> 2;

    // ---- A-frags via plain cached loads (compiler-scheduled) ----
    short8 afr[32];
    #pragma unroll
    for (int ks = 0; ks < 16; ++ks)
        afr[ks] = *(const short8*)(D.x + arow * 512 + ks * 32 + q * 8);
    if constexpr (KIND == 0) {
        #pragma unroll
        for (int ks = 0; ks < 16; ++ks) {
            const float* hp = D.hF + arow * THn + ks * 32 + q * 8;
            float4 v0 = *(const float4*)(hp);
            float4 v1 = *(const float4*)(hp + 4);
            uint4 w = {pk2(v0.x, v0.y), pk2(v0.z, v0.w),
                       pk2(v1.x, v1.y), pk2(v1.z, v1.w)};
            afr[16 + ks] = __builtin_bit_cast(short8, w);
        }
    } else {
        #pragma unroll
        for (int ks = 0; ks < 16; ++ks)
            afr[16 + ks] = *(const short8*)(D.hB + arow * 512 + ks * 32 + q * 8);
    }
    float cin0 = 0.f, cin1 = 0.f;
    if constexpr (KIND == 2) {
        const int row = row0 + q * 4 + g;
        cin0 = D.cin[(long)row * 512 + jt * 8 + cu];
        cin1 = D.cin[(long)row * 512 + jt * 8 + 4 + cu];
    }

    // ---- K loop: B-frags from LDS (contiguous 1024B per wave-fragment) ----
    floatx4 acc0 = {0.f, 0.f, 0.f, 0.f};
    floatx4 acc1 = {0.f, 0.f, 0.f, 0.f};
    const char* base = chunk + (c * 64 + q * 16);
    #pragma unroll
    for (int ks = 0; ks < 32; ++ks) {
        short8 b0 = *(const short8*)(base + ks * 2048);
        short8 b1 = *(const short8*)(base + ks * 2048 + 1024);
        acc0 = __builtin_amdgcn_mfma_f32_16x16x32_bf16(afr[ks], b0, acc0, 0, 0, 0);
        acc1 = __builtin_amdgcn_mfma_f32_16x16x32_bf16(afr[ks], b1, acc1, 0, 0, 0);
    }

    // ---- fused epilogue: gather 4 gates within each lane-quad; lane owns row q*4+g ----
    #pragma unroll
    for (int nf = 0; nf < 2; ++nf) {
        floatx4 acc = nf ? acc1 : acc0;
        float s0 = selc(acc, g);
        float s1 = __shfl_xor(selc(acc, g ^ 1), 1);
        float s2 = __shfl_xor(selc(acc, g ^ 2), 2);
        float s3 = __shfl_xor(selc(acc, g ^ 3), 3);
        float iv = sel4(s0, s1, s2, s3, g)     + bias[nf][0];
        float fv = sel4(s0, s1, s2, s3, g ^ 1) + bias[nf][1];
        float gv = sel4(s0, s1, s2, s3, g ^ 2) + bias[nf][2];
        float ov = sel4(s0, s1, s2, s3, g ^ 3) + bias[nf][3];

        const int row = row0 + q * 4 + g;
        const int jglob = jt * 8 + nf * 4 + cu;
        float cold;
        if constexpr (KIND == 0)      cold = 0.f;
        else if constexpr (KIND == 2) cold = nf ? cin1 : cin0;
        else                          cold = cst[nf];
        float si = 1.f / (1.f + expf(-iv));
        float sf = 1.f / (1.f + expf(-fv));
        float so = 1.f / (1.f + expf(-ov));
        float cn = sf * cold + si * tanhf(gv);
        float hn = so * tanhf(cn);

        st16_sc(D.hOutB + (long)row * 512 + jglob, f2bf(hn));
        if constexpr (KIND == 0 || KIND == 2) {
            st32_sc(D.coutA + (long)row * D.cAs + jglob, cn);
        }
        if constexpr (KIND == 2) {
            st32_sc(D.hOut2 + (long)row * THn + jglob, hn);
        }
        if constexpr (KIND == 1 || KIND == 3) {
            cst[nf] = cn;
            if (D.hOut2) {
                st32_sc(D.hOut2 + (long)row * 1024 + jglob, hn);
                st32_sc(D.cOut2 + (long)row * 1024 + jglob, cn);
            }
        }
    }
}

__global__ __launch_bounds__(256, 1) void grid_lstm_persist(Params P) {
    __shared__ char smem[2 * 65536];   // [A-role chunk][B-role chunk]

    const int tid = threadIdx.x;
    const int lane = tid & 63;
    const int wid = tid >> 6;
    const int c = lane & 15;
    const int q = lane >> 4;
    const int blk = blockIdx.x;
    const int pair = blk >> 1;
    const int half = blk & 1;          // row half: rows [half*64, half*64+64)
    const int jt = pair & 63;
    const bool hiPair = pair >= 64;
    const int cellA = hiPair ? 3 : 0;  // c11 : c00
    const int cellB = hiPair ? 2 : 1;  // c10 : c01
    const int leafIdx = blk & 7;

    // ---- prologue: weights fp32 -> bf16 -> LDS (once), biases -> registers ----
    loadChunk(smem,         P.Wih, P.Whh, cellA, jt, tid);
    loadChunk(smem + 65536, P.Wih, P.Whh, cellB, jt, tid);

    float biasA[2][4], biasB[2][4];
    {
        const int cuu = c >> 2;
        #pragma unroll
        for (int nf = 0; nf < 2; ++nf) {
            int j = jt * 8 + nf * 4 + cuu;
            #pragma unroll
            for (int g2 = 0; g2 < 4; ++g2) {
                long ia = (long)cellA * 2048 + (long)g2 * 512 + j;
                long ib = (long)cellB * 2048 + (long)g2 * 512 + j;
                biasA[nf][g2] = P.bih[ia] + P.bhh[ia];
                biasB[nf][g2] = P.bih[ib] + P.bhh[ib];
            }
        }
    }
    __syncthreads();

    const int row0 = half * 64 + wid * 16;
    float cst[2] = {0.f, 0.f};         // block-private layer cell state (c01 / c11)
    float cstDummy[2] = {0.f, 0.f};

    for (int r = 0; r < NROUND; ++r) {
        const int t = r >> 1;
        const bool stB = (r & 1) != 0;

        if (!stB) {
            if (!hiPair) {                      // c00(t): x=H1[p][0], h=H0in[t] fp32
                if (t < Tn) {
                    int p = t & 1;
                    RoundDesc D{};
                    D.x = P.H1b + ((long)p * 2 + 0) * LBH;
                    D.hF = P.H0in + (long)t * Hn;
                    D.hOutB = P.h0A;
                    D.coutA = P.m0; D.cAs = 512;
                    runCell<0>(D, smem, biasA, jt, row0, c, q, cstDummy);
                }
            } else {                            // c11(t-1)
                int tc = t - 1;
                if (tc >= 0) {
                    int p = tc & 1;
                    RoundDesc D{};
                    D.x = P.h0B;
                    D.hB = P.H1b + ((long)p * 2 + 1) * LBH;
                    D.hOutB = P.H1b + ((long)(1 - p) * 2 + 1) * LBH;
                    if (tc == Tn - 1) {
                        D.hOut2 = P.outH1 + Hn;
                        D.cOut2 = P.outM1 + Hn;
                    }
                    runCell<3>(D, smem, biasA, jt, row0, c, q, cst);
                }
            }
        } else {
            int p = t & 1;
            if (!hiPair) {                      // c01(t): x=h0A, h=H1[p][0]
                RoundDesc D{};
                D.x = P.h0A;
                D.hB = P.H1b + ((long)p * 2 + 0) * LBH;
                D.hOutB = P.H1b + ((long)(1 - p) * 2 + 0) * LBH;
                if (t == Tn - 1) {
                    D.hOut2 = P.outH1;
                    D.cOut2 = P.outM1;
                }
                runCell<1>(D, smem + 65536, biasB, jt, row0, c, q, cst);
            } else {                            // c10(t): x=H1[p][1], h=h0A
                RoundDesc D{};
                D.x = P.H1b + ((long)p * 2 + 1) * LBH;
                D.hB = P.h0A;
                D.cin = P.m0;
                D.hOutB = P.h0B;
                D.coutA = P.outM0 + (long)t * Hn; D.cAs = THn;
                D.hOut2 = P.outH0 + (long)t * Hn;
                runCell<2>(D, smem + 65536, biasB, jt, row0, c, q, cstDummy);
            }
        }
        if (r + 1 < NROUND) gridBarrier(P.bar, leafIdx, (unsigned)r);
    }
}

extern "C" void kernel_launch(void* const* d_in, const int* in_sizes, int n_in,
                              void* d_out, int out_size, void* d_ws, size_t ws_size,
                              hipStream_t stream) {
    (void)in_sizes; (void)n_in; (void)out_size; (void)ws_size;
    const float* H0in = (const float*)d_in[0];
    const float* Wih  = (const float*)d_in[1];
    const float* Whh  = (const float*)d_in[2];
    const float* bih  = (const float*)d_in[3];
    const float* bhh  = (const float*)d_in[4];
    float* out = (float*)d_out;

    // workspace: bf16 recurrent bufs + fp32 m0 + barrier counters (~1.1 MB)
    unsigned short* h0A = (unsigned short*)d_ws;
    unsigned short* h0B = h0A + LBH;
    unsigned short* H1b = h0B + LBH;                  // [2][2][B][H] bf16
    float* m0 = (float*)(H1b + 4 * LBH);              // [B][H] fp32
    unsigned* bar = (unsigned*)(m0 + LBH);            // leaf[8]@stride16 + root@128

    size_t zeroBytes = (size_t)((char*)(bar + 256) - (char*)d_ws);
    hipMemsetAsync(d_ws, 0, zeroBytes, stream);

    Params P;
    P.H0in = H0in; P.Wih = Wih; P.Whh = Whh; P.bih = bih; P.bhh = bhh;
    P.h0A = h0A; P.h0B = h0B; P.H1b = H1b; P.m0 = m0;
    P.outH0 = out;
    P.outH1 = out + (long)Bn * THn;
    P.outM0 = P.outH1 + 2 * LBH;
    P.outM1 = P.outM0 + (long)Bn * THn;
    P.bar = bar;

    void* args[] = {&P};
    hipLaunchCooperativeKernel((void*)grid_lstm_persist, dim3(NBLK), dim3(256),
                               args, 0, stream);
}